// Round 7
// baseline (211.321 us; speedup 1.0000x reference)
//
#include <hip/hip_runtime.h>
#include <hip/hip_bf16.h>

#define B_  256
#define H_  1024
#define D_  256
#define G_  32
#define C_  16
#define O_  256
#define HD_ 1280          // H + D
#define N1_ 16384         // C*H

typedef __attribute__((ext_vector_type(8)))  short short8;
typedef __attribute__((ext_vector_type(4)))  short s16x4;
typedef __attribute__((ext_vector_type(4)))  float f32x4;
typedef __attribute__((ext_vector_type(16))) float f32x16;

#define MFMA32(a, b, c) __builtin_amdgcn_mfma_f32_32x32x16_bf16((a), (b), (c), 0, 0, 0)

// tanh via fast exp + hw rcp; clamped to +-(1-6e-8) so that the downstream
// blend denominator 1 + tA*tB is always > 0 (never 0*inf = NaN).
__device__ __forceinline__ float tanh_c(float x) {
    float y = __expf(2.f * x);
    float t = 1.f - 2.f * __builtin_amdgcn_rcpf(y + 1.f);
    return fminf(fmaxf(t, -0.99999994f), 0.99999994f);
}

// Split fp32 into bf16 hi + bf16 lo (both truncated).
__device__ __forceinline__ short bfhi(float x) {
    return (short)(__float_as_uint(x) >> 16);
}
__device__ __forceinline__ short bflo(float x) {
    float fhi = __uint_as_float(__float_as_uint(x) & 0xFFFF0000u);
    return (short)(__float_as_uint(x - fhi) >> 16);
}

__device__ __forceinline__ void split4(const float4 v, s16x4& hi, s16x4& lo) {
    hi[0] = bfhi(v.x); lo[0] = bflo(v.x);
    hi[1] = bfhi(v.y); lo[1] = bflo(v.y);
    hi[2] = bfhi(v.z); lo[2] = bflo(v.z);
    hi[3] = bfhi(v.w); lo[3] = bflo(v.w);
}

// ---------------------------------------------------------------------------
// Kernel 1: tA[b, c*H+o] = tanh( sum_h hidden[b,h]*attn_w[c,o,h] + attn_b[c,o] )
// GEMM M=256, N=16384, K=1024.  BM=256 x BN=32, BK=32, grid 512 (1-D).
// Round-7: OCCUPANCY.  Rounds 4-6 proved staging leanness doesn't move dur at
// 8 waves/CU (2/SIMD) -- the per-slab wait+barrier is exposed because nothing
// else is resident.  Now 512 threads / 8 waves per block, wave tile 32x32
// (1 acc, one 32-row m-strip each) => 4096 waves = 16 waves/CU = 4/SIMD.
//   - all 8 waves read the SAME B fragments from LDS (broadcast reads);
//   - B staged by lanes<32 of EVERY wave (one masked width-16 DMA per wave
//     per slab -> per-wave vmcnt is uniform; steady count = 1, never 0);
//   - A: prepacked bf16 hi/lo fragments (gemm2 prepass), L2-resident, loaded
//     1 slab ahead into parity register sets (4 x b128 / wave / slab);
//   - B fp32 in LDS, XOR-16B-chunk swizzle (source-permuted, same involution
//     on read); 4-deep DMA ring; ONE barrier per slab; setprio on MFMA.
// ---------------------------------------------------------------------------
__global__ __launch_bounds__(512, 4) void gemm1_kernel(
    const short* __restrict__ hidH, const short* __restrict__ hidL,
    const float* __restrict__ attn_w, const float* __restrict__ attn_b,
    float* __restrict__ hp)
{
    __shared__ float Bsf[4][32 * 32];     // 4-deep DMA ring, 4 KB/slab

    const int tid  = threadIdx.x;
    const int wave = tid >> 6, lane = tid & 63;
    const int l31  = lane & 31;
    const int hi2  = (lane >> 5) * 2;     // k-half chunk base (16B chunks)
    const int sw   = l31 & 7;             // read-side XOR swizzle
    const int n0   = blockIdx.x * 32;

    f32x16 acc;
    #pragma unroll
    for (int i = 0; i < 16; ++i) acc[i] = 0.f;

    // DMA source: lanes 0-31 of wave w stage rows 4w..4w+3 (lane>>3 selects
    // row, lane&7 the 16B phys chunk; phys chunk c holds logical c^(row&7)).
    const int rD = wave * 4 + (lane >> 3);
    const int cD = (lane & 7) ^ (rD & 7);
    const float* pBsrc = attn_w + (size_t)(n0 + rD) * HD_ + cD * 4;

    // A fragment base (hidP layout: [s][k0][ks][lane][8] shorts; this wave
    // owns strip s = wave = rows wave*32 .. wave*32+31).
    const size_t aBase = (size_t)wave * 32768 + (size_t)lane * 8;
    const short* pH = hidH + aBase;
    const short* pL = hidL + aBase;

    short8 aH[2][2], aL[2][2];            // [parity][ks]

#define LOADA(SET, K)                                                         \
    {                                                                         \
        const int o_ = (K) * 1024;                                            \
        aH[SET][0] = *(const short8*)(pH + o_);                               \
        aH[SET][1] = *(const short8*)(pH + o_ + 512);                         \
        aL[SET][0] = *(const short8*)(pL + o_);                               \
        aL[SET][1] = *(const short8*)(pL + o_ + 512);                         \
    }

#define DMAB(BUF, K)                                                          \
    if (lane < 32)                                                            \
        __builtin_amdgcn_global_load_lds(                                     \
            (const __attribute__((address_space(1))) void*)(pBsrc + (K) * 32),\
            (__attribute__((address_space(3))) void*)(&Bsf[BUF][wave * 128]), \
            16, 0, 0);

    // Read logical chunk kc of row l31 at phys chunk kc ^ sw; split to hi/lo.
#define READB(BUF, KS, BH, BL)                                                \
    {                                                                         \
        const float* rp_ = &Bsf[BUF][l31 * 32];                               \
        const int kc_ = (KS) * 4 + hi2;                                       \
        float4 ca_ = *(const float4*)(rp_ + ((kc_    ) ^ sw) * 4);            \
        float4 cb_ = *(const float4*)(rp_ + ((kc_ + 1) ^ sw) * 4);            \
        s16x4 h0_, lo0_, h1_, lo1_;                                           \
        split4(ca_, h0_, lo0_);                                               \
        split4(cb_, h1_, lo1_);                                               \
        BH = short8{h0_[0],h0_[1],h0_[2],h0_[3],h1_[0],h1_[1],h1_[2],h1_[3]}; \
        BL = short8{lo0_[0],lo0_[1],lo0_[2],lo0_[3],                          \
                    lo1_[0],lo1_[1],lo1_[2],lo1_[3]};                         \
    }

    // Per-iter: counted vmcnt (own DMA(K) + own A(K) done; newer DMAs stay in
    // flight), barrier, A(K+1) prefetch, DMA(K+3) issue (order pinned so the
    // counts are exact), read+split B(K), 6 MFMA.  One barrier per slab.
#define ITER(P, K, VC, DOL, DODMA)                                            \
    {                                                                         \
        asm volatile("s_waitcnt vmcnt(" #VC ")" ::: "memory");                \
        __builtin_amdgcn_s_barrier();                                         \
        if (DOL) LOADA(P ^ 1, (K) + 1)                                        \
        __builtin_amdgcn_sched_barrier(0);                                    \
        if (DODMA) DMAB(((K) + 3) & 3, (K) + 3)                               \
        __builtin_amdgcn_sched_barrier(0);                                    \
        short8 bh0, bl0, bh1, bl1;                                            \
        READB((K) & 3, 0, bh0, bl0)                                           \
        READB((K) & 3, 1, bh1, bl1)                                           \
        __builtin_amdgcn_s_setprio(1);                                        \
        acc = MFMA32(aH[P][0], bh0, acc);                                     \
        acc = MFMA32(aL[P][0], bh0, acc);                                     \
        acc = MFMA32(aH[P][0], bl0, acc);                                     \
        acc = MFMA32(aH[P][1], bh1, acc);                                     \
        acc = MFMA32(aL[P][1], bh1, acc);                                     \
        acc = MFMA32(aH[P][1], bl1, acc);                                     \
        __builtin_amdgcn_s_setprio(0);                                        \
    }

    // Prologue (queue order: D0, A0x4, D1, D2 -> k=0 waits vmcnt(2)).
    DMAB(0, 0)
    __builtin_amdgcn_sched_barrier(0);
    LOADA(0, 0)
    __builtin_amdgcn_sched_barrier(0);
    DMAB(1, 1)
    DMAB(2, 2)

    // vmcnt: k=0 -> 2; k=1..29 -> 1 (queue: D(k), D(k+1)/A(k), newer D(k+2));
    // k=30,31 -> 0 (A(k) is the newest outstanding; ring drained).
    ITER(0, 0, 2, 1, 1)
    for (int k = 1; k <= 27; k += 2) {
        ITER(1, k,     1, 1, 1)
        ITER(0, k + 1, 1, 1, 1)
    }
    ITER(1, 29, 1, 1, 0)
    ITER(0, 30, 0, 1, 0)
    ITER(1, 31, 0, 0, 0)
#undef ITER
#undef READB
#undef DMAB
#undef LOADA

    // 32x32 C/D layout: col = lane&31, row = (r&3) + 8*(r>>2) + 4*(lane>>5).
    const int col  = n0 + l31;
    const float bias = attn_b[col];
    const int rbase = wave * 32 + (lane >> 5) * 4;
    float* dcol = hp + col;
    #pragma unroll
    for (int r = 0; r < 16; ++r) {
        const int row = rbase + (r & 3) + 8 * (r >> 2);
        dcol[(size_t)row * N1_] = tanh_c(acc[r] + bias);
    }
}

// ---------------------------------------------------------------------------
// Kernel 2: tB[c,g,o] = tanh( sum_d enc[c,g,d] * attn_w[c,o,H+d] )
// Per-c GEMM M=32, N=1024, K=256; grid (16,16)=256 blocks.
// Prepass folded in: pack hidden (B,H) into bf16 hi/lo planes in MFMA-
// FRAGMENT order for gemm1's register-direct A loads:
//   hidP[s][k0][ks][lane][j] = hid[s*32+(lane&31)][k0*32+ks*16+(lane>>5)*8+j]
// ---------------------------------------------------------------------------
__global__ __launch_bounds__(256) void gemm2_kernel(
    const float* __restrict__ enc, const float* __restrict__ attn_w,
    const float* __restrict__ hidden, float* __restrict__ ep,
    short* __restrict__ hidH, short* __restrict__ hidL)
{
    const int tid  = threadIdx.x;
    const int wave = tid >> 6, lane = tid & 63;

    {   // fragment-pack prepass: 32768 lane-tasks over the first 128 blocks
        const int bid = blockIdx.y * 16 + blockIdx.x;
        const int gid = bid * 256 + tid;
        if (gid < 32768) {
            const int s   = gid >> 12;
            const int k0  = (gid >> 7) & 31;
            const int ks  = (gid >> 6) & 1;
            const int ln  = gid & 63;
            const int row = s * 32 + (ln & 31);
            const int colk = k0 * 32 + ks * 16 + (ln >> 5) * 8;
            const float* src = hidden + (size_t)row * H_ + colk;
            s16x4 h0, l0, h1, l1;
            split4(*(const float4*)src, h0, l0);
            split4(*(const float4*)(src + 4), h1, l1);
            *(short8*)(hidH + (size_t)gid * 8) =
                short8{h0[0],h0[1],h0[2],h0[3],h1[0],h1[1],h1[2],h1[3]};
            *(short8*)(hidL + (size_t)gid * 8) =
                short8{l0[0],l0[1],l0[2],l0[3],l1[0],l1[1],l1[2],l1[3]};
        }
    }

    const int c  = blockIdx.y;
    const int n0 = blockIdx.x * 64 + wave * 16;   // o tile, 16 per wave
    const int l16 = lane & 15;
    const int lk  = (lane >> 4) * 8;

#define MFMA16(a, b, c) __builtin_amdgcn_mfma_f32_16x16x32_bf16((a), (b), (c), 0, 0, 0)
    f32x4 acc[2];
    acc[0] = f32x4{0.f, 0.f, 0.f, 0.f};
    acc[1] = f32x4{0.f, 0.f, 0.f, 0.f};

    const float* encp = enc + c * (G_ * D_);
    const float* wp   = attn_w + (size_t)c * H_ * HD_ + H_;

    #pragma unroll
    for (int kk = 0; kk < 8; ++kk) {
        const int k0 = kk * 32 + lk;
        short8 ah[2], al[2], bh, bl;
        #pragma unroll
        for (int mi = 0; mi < 2; ++mi) {
            const float* p = encp + (mi * 16 + l16) * D_ + k0;
            s16x4 h0, l0, h1, l1;
            split4(*(const float4*)p, h0, l0);
            split4(*(const float4*)(p + 4), h1, l1);
            ah[mi] = short8{h0[0],h0[1],h0[2],h0[3],h1[0],h1[1],h1[2],h1[3]};
            al[mi] = short8{l0[0],l0[1],l0[2],l0[3],l1[0],l1[1],l1[2],l1[3]};
        }
        {
            const float* p = wp + (size_t)(n0 + l16) * HD_ + k0;
            s16x4 h0, l0, h1, l1;
            split4(*(const float4*)p, h0, l0);
            split4(*(const float4*)(p + 4), h1, l1);
            bh = short8{h0[0],h0[1],h0[2],h0[3],h1[0],h1[1],h1[2],h1[3]};
            bl = short8{l0[0],l0[1],l0[2],l0[3],l1[0],l1[1],l1[2],l1[3]};
        }
        #pragma unroll
        for (int mi = 0; mi < 2; ++mi) {
            acc[mi] = MFMA16(ah[mi], bh, acc[mi]);
            acc[mi] = MFMA16(al[mi], bh, acc[mi]);
            acc[mi] = MFMA16(ah[mi], bl, acc[mi]);
        }
    }

    const int lr = (lane >> 4) * 4;
    #pragma unroll
    for (int mi = 0; mi < 2; ++mi) {
        const int g = mi * 16 + lr;
        const int o = n0 + l16;
        float* dst = ep + (c * G_ + g) * H_ + o;
        f32x4 vacc = acc[mi];
        dst[0]      = tanh_c(vacc[0]);
        dst[H_]     = tanh_c(vacc[1]);
        dst[2 * H_] = tanh_c(vacc[2]);
        dst[3 * H_] = tanh_c(vacc[3]);
    }
#undef MFMA16
}

// ---------------------------------------------------------------------------
// Kernel 3: per (c, 4 b's): scores[g] = sum_h blend(tA,tB)*v where
// blend = (tA+tB)/(1+tA*tB) = tanh(A+B) exactly; softmax over g; att_cat out;
// weighted[b,c,d] = sum_g att*enc.
// ---------------------------------------------------------------------------
__global__ __launch_bounds__(256) void attn_kernel(
    const float* __restrict__ hp, const float* __restrict__ ep,
    const float* __restrict__ v, const float* __restrict__ enc,
    float* __restrict__ out, float* __restrict__ wt)
{
    const int c  = blockIdx.x;
    const int b0 = blockIdx.y * 4;
    const int tid  = threadIdx.x;
    const int wave = tid >> 6, lane = tid & 63;

    __shared__ float s_att[4][G_];
    __shared__ float s_sc[4][G_];

    // h index mapping: h = lane*4 + j*256 + e  (same partition for hp/ep/v)
    f32x4 vv[4], tav[4][4];
    const float* vrow = v + c * H_;
    #pragma unroll
    for (int j = 0; j < 4; ++j)
        vv[j] = *(const f32x4*)(vrow + lane * 4 + j * 256);
    #pragma unroll
    for (int bi = 0; bi < 4; ++bi) {
        const float* hprow = hp + (size_t)(b0 + bi) * N1_ + c * H_;
        #pragma unroll
        for (int j = 0; j < 4; ++j)
            tav[bi][j] = *(const f32x4*)(hprow + lane * 4 + j * 256);
    }

    #pragma unroll
    for (int gg = 0; gg < 8; ++gg) {
        const int g = wave * 8 + gg;
        const float* eprow = ep + (size_t)(c * G_ + g) * H_;
        float s[4] = {0.f, 0.f, 0.f, 0.f};
        #pragma unroll
        for (int j = 0; j < 4; ++j) {
            const f32x4 tb = *(const f32x4*)(eprow + lane * 4 + j * 256);
            #pragma unroll
            for (int e = 0; e < 4; ++e) {
                const float tbx = tb[e];
                const float w   = vv[j][e];
                #pragma unroll
                for (int bi = 0; bi < 4; ++bi) {
                    const float ta  = tav[bi][j][e];
                    const float num = ta + tbx;
                    const float den = fmaf(ta, tbx, 1.f);
                    s[bi] = fmaf(num * __builtin_amdgcn_rcpf(den), w, s[bi]);
                }
            }
        }
        #pragma unroll
        for (int off = 32; off > 0; off >>= 1) {
            s[0] += __shfl_down(s[0], off, 64);
            s[1] += __shfl_down(s[1], off, 64);
            s[2] += __shfl_down(s[2], off, 64);
            s[3] += __shfl_down(s[3], off, 64);
        }
        if (lane == 0) {
            s_sc[0][g] = s[0]; s_sc[1][g] = s[1];
            s_sc[2][g] = s[2]; s_sc[3][g] = s[3];
        }
    }
    __syncthreads();

    if (tid < 128) {
        const int bi = tid >> 5, g = tid & 31;
        float sv = s_sc[bi][g];
        float m = sv;
        #pragma unroll
        for (int off = 16; off > 0; off >>= 1)
            m = fmaxf(m, __shfl_xor(m, off, 32));
        const float e = __expf(sv - m);
        float sum = e;
        #pragma unroll
        for (int off = 16; off > 0; off >>= 1)
            sum += __shfl_xor(sum, off, 32);
        const float a = e / sum;
        s_att[bi][g] = a;
        out[(size_t)(b0 + bi) * (C_ * G_) + c * G_ + g] = a;   // att_cat
    }
    __syncthreads();

    // weighted[b,c,d], thread = d; enc element shared across the 4 b's
    float w0 = 0.f, w1 = 0.f, w2 = 0.f, w3 = 0.f;
    const float* encc = enc + c * (G_ * D_) + tid;
    #pragma unroll
    for (int g = 0; g < G_; ++g) {
        const float e = encc[g * D_];
        w0 = fmaf(s_att[0][g], e, w0);
        w1 = fmaf(s_att[1][g], e, w1);
        w2 = fmaf(s_att[2][g], e, w2);
        w3 = fmaf(s_att[3][g], e, w3);
    }
    wt[(size_t)((b0 + 0) * C_ + c) * D_ + tid] = w0;
    wt[(size_t)((b0 + 1) * C_ + c) * D_ + tid] = w1;
    wt[(size_t)((b0 + 2) * C_ + c) * D_ + tid] = w2;
    wt[(size_t)((b0 + 3) * C_ + c) * D_ + tid] = w3;
}

// ---------------------------------------------------------------------------
// Kernel 4: pooled[b,d] = mean_c weighted; out[b,o] = pooled.out_w[o,:] + out_b
// ---------------------------------------------------------------------------
__global__ __launch_bounds__(256) void out_kernel(
    const float* __restrict__ wt, const float* __restrict__ out_w,
    const float* __restrict__ out_b, float* __restrict__ out)
{
    const int b = blockIdx.x, tid = threadIdx.x;
    __shared__ float pooled[D_];

    float s = 0.f;
    #pragma unroll
    for (int c = 0; c < C_; ++c)
        s += wt[(size_t)(b * C_ + c) * D_ + tid];
    pooled[tid] = s * (1.f / 16.f);
    __syncthreads();

    float acc = out_b[tid];
    const float* wrow = out_w + tid * D_;
    #pragma unroll 8
    for (int dc = 0; dc < 64; ++dc) {
        float4 w4 = *(const float4*)(wrow + dc * 4);
        acc += pooled[dc * 4 + 0] * w4.x;
        acc += pooled[dc * 4 + 1] * w4.y;
        acc += pooled[dc * 4 + 2] * w4.z;
        acc += pooled[dc * 4 + 3] * w4.w;
    }
    out[(size_t)B_ * (C_ * G_) + b * O_ + tid] = acc;
}

extern "C" void kernel_launch(void* const* d_in, const int* in_sizes, int n_in,
                              void* d_out, int out_size, void* d_ws, size_t ws_size,
                              hipStream_t stream) {
    const float* hidden = (const float*)d_in[0];   // (B,H)     fp32
    const float* enc    = (const float*)d_in[1];   // (C,G,D)   fp32
    const float* attn_w = (const float*)d_in[2];   // (C,H,H+D) fp32
    const float* attn_b = (const float*)d_in[3];   // (C,H)     fp32
    const float* v      = (const float*)d_in[4];   // (C,H)     fp32
    const float* out_w  = (const float*)d_in[5];   // (O,D)     fp32
    const float* out_b  = (const float*)d_in[6];   // (O,)      fp32
    float* out = (float*)d_out;                    // att_cat (B,C*G) ++ out (B,O)

    float* hp = (float*)d_ws;                      // (B, C*H)  tA fp32: 16.78 MB
    float* ep = hp + (size_t)B_ * N1_;             // (C, G, H) tB fp32:  2.10 MB
    float* wt = ep + (size_t)C_ * G_ * H_;         // (B, C, D) fp32:     4.19 MB
    short* hidH = (short*)(wt + (size_t)B_ * C_ * D_);  // (B,H) bf16 hi frag-packed: 512 KB
    short* hidL = hidH + (size_t)B_ * H_;               // (B,H) bf16 lo frag-packed: 512 KB

    // gemm2 first: it also produces the fragment-packed hidden planes gemm1 reads.
    gemm2_kernel<<<dim3(16, C_), 256, 0, stream>>>(enc, attn_w, hidden, ep, hidH, hidL);
    gemm1_kernel<<<512, 512, 0, stream>>>(hidH, hidL, attn_w, attn_b, hp);
    attn_kernel<<<dim3(C_, B_ / 4), 256, 0, stream>>>(hp, ep, v, enc, out, wt);
    out_kernel<<<B_, 256, 0, stream>>>(wt, out_w, out_b, out);
}